// Round 14
// baseline (361.256 us; speedup 1.0000x reference)
//
#include <hip/hip_runtime.h>
#include <math.h>

#define H 8
#define DM 512
#define DK 64
#define LQ 1024
#define LK 2048
#define BATCH 4
#define LN_EPS 1e-5f

typedef short s16x8 __attribute__((ext_vector_type(8)));
typedef float f32x16 __attribute__((ext_vector_type(16)));

union U32x4 { unsigned u[4]; s16x8 v; };

// f32 -> bf16 (RNE), bits in low 16
__device__ __forceinline__ unsigned f2bf_rne(unsigned u) {
    return (u + 0x7fffu + ((u >> 16) & 1u)) >> 16;
}
__device__ __forceinline__ void cvt_split(float x, short& h, short& l) {
    unsigned u = __float_as_uint(x);
    unsigned hb = f2bf_rne(u);
    float hf = __uint_as_float(hb << 16);
    unsigned lb = f2bf_rne(__float_as_uint(x - hf));
    h = (short)hb; l = (short)lb;
}
__device__ __forceinline__ unsigned pack_bf16(float a, float b) {
    return f2bf_rne(__float_as_uint(a)) | (f2bf_rne(__float_as_uint(b)) << 16);
}

// ---------------------------------------------------------------------------
// Split-bf16 MFMA GEMM body (validated). LDS passed in by caller.
// MODE: 0 f32 C (+resid); 1 K->bf16 hi/lo [b][h][key][d]; 2 V^T hi/lo.
// ---------------------------------------------------------------------------
#define LDP 40

template <int MODE>
__device__ __forceinline__ void gemm_mfma_body(short* __restrict__ Ah,
                                               short* __restrict__ Al,
                                               short* __restrict__ Bh,
                                               short* __restrict__ Bl,
                                               const float* __restrict__ A,
                                               const float* __restrict__ W,
                                               const float* __restrict__ bias,
                                               const float* __restrict__ resid,
                                               float* __restrict__ C,
                                               short* __restrict__ dsth,
                                               short* __restrict__ dstl,
                                               long m0, int n0)
{
    const int tid = threadIdx.x;
    const int l   = tid & 63;
    const int w   = tid >> 6;
    const int wm  = w >> 1, wn = w & 1;

    f32x16 acc[2][2];
#pragma unroll
    for (int mi = 0; mi < 2; ++mi)
#pragma unroll
        for (int ni = 0; ni < 2; ++ni)
#pragma unroll
            for (int e = 0; e < 16; ++e) acc[mi][ni][e] = 0.f;

    const int srow = tid >> 1;
    const int skb  = (tid & 1) * 16;

    for (int k0 = 0; k0 < DM; k0 += 32) {
        __syncthreads();
        {
            const float* src = A + (m0 + srow) * DM + k0 + skb;
            float fa[16];
            *(float4*)&fa[0]  = *(const float4*)(src + 0);
            *(float4*)&fa[4]  = *(const float4*)(src + 4);
            *(float4*)&fa[8]  = *(const float4*)(src + 8);
            *(float4*)&fa[12] = *(const float4*)(src + 12);
            s16x8 vh0, vl0, vh1, vl1;
#pragma unroll
            for (int j = 0; j < 8; ++j) { short hh, ll; cvt_split(fa[j], hh, ll); vh0[j] = hh; vl0[j] = ll; }
#pragma unroll
            for (int j = 0; j < 8; ++j) { short hh, ll; cvt_split(fa[8 + j], hh, ll); vh1[j] = hh; vl1[j] = ll; }
            *(s16x8*)&Ah[srow * LDP + skb]     = vh0;
            *(s16x8*)&Ah[srow * LDP + skb + 8] = vh1;
            *(s16x8*)&Al[srow * LDP + skb]     = vl0;
            *(s16x8*)&Al[srow * LDP + skb + 8] = vl1;
        }
        {
            const float* src = W + (long)(n0 + srow) * DM + k0 + skb;
            float fb[16];
            *(float4*)&fb[0]  = *(const float4*)(src + 0);
            *(float4*)&fb[4]  = *(const float4*)(src + 4);
            *(float4*)&fb[8]  = *(const float4*)(src + 8);
            *(float4*)&fb[12] = *(const float4*)(src + 12);
            s16x8 vh0, vl0, vh1, vl1;
#pragma unroll
            for (int j = 0; j < 8; ++j) { short hh, ll; cvt_split(fb[j], hh, ll); vh0[j] = hh; vl0[j] = ll; }
#pragma unroll
            for (int j = 0; j < 8; ++j) { short hh, ll; cvt_split(fb[8 + j], hh, ll); vh1[j] = hh; vl1[j] = ll; }
            *(s16x8*)&Bh[srow * LDP + skb]     = vh0;
            *(s16x8*)&Bh[srow * LDP + skb + 8] = vh1;
            *(s16x8*)&Bl[srow * LDP + skb]     = vl0;
            *(s16x8*)&Bl[srow * LDP + skb + 8] = vl1;
        }
        __syncthreads();

#pragma unroll
        for (int kk = 0; kk < 32; kk += 16) {
            const int ko = kk + (l >> 5) * 8;
            s16x8 ah[2], al2[2], bh[2], bl[2];
#pragma unroll
            for (int mi = 0; mi < 2; ++mi) {
                int r = wm * 64 + mi * 32 + (l & 31);
                ah[mi]  = *(const s16x8*)&Ah[r * LDP + ko];
                al2[mi] = *(const s16x8*)&Al[r * LDP + ko];
            }
#pragma unroll
            for (int ni = 0; ni < 2; ++ni) {
                int r = wn * 64 + ni * 32 + (l & 31);
                bh[ni] = *(const s16x8*)&Bh[r * LDP + ko];
                bl[ni] = *(const s16x8*)&Bl[r * LDP + ko];
            }
#pragma unroll
            for (int mi = 0; mi < 2; ++mi)
#pragma unroll
                for (int ni = 0; ni < 2; ++ni) {
                    acc[mi][ni] = __builtin_amdgcn_mfma_f32_32x32x16_bf16(ah[mi],  bh[ni], acc[mi][ni], 0, 0, 0);
                    acc[mi][ni] = __builtin_amdgcn_mfma_f32_32x32x16_bf16(ah[mi],  bl[ni], acc[mi][ni], 0, 0, 0);
                    acc[mi][ni] = __builtin_amdgcn_mfma_f32_32x32x16_bf16(al2[mi], bh[ni], acc[mi][ni], 0, 0, 0);
                }
        }
    }

#pragma unroll
    for (int mi = 0; mi < 2; ++mi)
#pragma unroll
        for (int ni = 0; ni < 2; ++ni) {
            const int n = n0 + wn * 64 + ni * 32 + (l & 31);
            const float bv = bias[n];
            const long mbase = m0 + wm * 64 + mi * 32 + 4 * (l >> 5);
#pragma unroll
            for (int reg = 0; reg < 16; ++reg) {
                long m = mbase + (reg & 3) + 8 * (reg >> 2);
                float val = acc[mi][ni][reg] + bv;
                if (MODE == 0) {
                    if (resid) val += resid[m * DM + n];
                    C[m * DM + n] = val;
                } else {
                    short hv, lv; cvt_split(val, hv, lv);
                    int b2 = (int)(m >> 11), key = (int)(m & 2047);
                    int h2 = n >> 6, d = n & 63;
                    if (MODE == 1) {
                        long idx = ((long)(b2 * 8 + h2) * 2048 + key) * 64 + d;
                        dsth[idx] = hv; dstl[idx] = lv;
                    } else {
                        long idx = ((long)(b2 * 8 + h2) * 64 + d) * 2048 + key;
                        dsth[idx] = hv; dstl[idx] = lv;
                    }
                }
            }
        }
}

// Merged projections: Q:128 (f32 out), K:256 (bf16 hi/lo), V:256 (bf16^T hi/lo)
__global__ __launch_bounds__(256, 4) void qkv_kernel(const float* __restrict__ Q,
                                                     const float* __restrict__ K,
                                                     const float* __restrict__ V,
                                                     const float* __restrict__ Wq,
                                                     const float* __restrict__ bq,
                                                     const float* __restrict__ Wk,
                                                     const float* __restrict__ bk,
                                                     const float* __restrict__ Wv,
                                                     const float* __restrict__ bv,
                                                     float* __restrict__ qp,
                                                     short* __restrict__ kbh,
                                                     short* __restrict__ kbl,
                                                     short* __restrict__ vth,
                                                     short* __restrict__ vtl)
{
    __shared__ __align__(16) short Ah[128 * LDP];
    __shared__ __align__(16) short Al[128 * LDP];
    __shared__ __align__(16) short Bh[128 * LDP];
    __shared__ __align__(16) short Bl[128 * LDP];

    const int bx = blockIdx.x;
    if (bx < 128) {
        gemm_mfma_body<0>(Ah, Al, Bh, Bl, Q, Wq, bq, nullptr, qp, nullptr, nullptr,
                          (long)(bx >> 2) * 128, (bx & 3) * 128);
    } else if (bx < 384) {
        int t = bx - 128;
        gemm_mfma_body<1>(Ah, Al, Bh, Bl, K, Wk, bk, nullptr, nullptr, kbh, kbl,
                          (long)(t >> 2) * 128, (t & 3) * 128);
    } else {
        int t = bx - 384;
        gemm_mfma_body<2>(Ah, Al, Bh, Bl, V, Wv, bv, nullptr, nullptr, vth, vtl,
                          (long)(t >> 2) * 128, (t & 3) * 128);
    }
}

__global__ __launch_bounds__(256, 4) void ogemm_kernel(const float* __restrict__ A,
                                                       const float* __restrict__ W,
                                                       const float* __restrict__ bias,
                                                       const float* __restrict__ resid,
                                                       float* __restrict__ C)
{
    __shared__ __align__(16) short Ah[128 * LDP];
    __shared__ __align__(16) short Al[128 * LDP];
    __shared__ __align__(16) short Bh[128 * LDP];
    __shared__ __align__(16) short Bl[128 * LDP];

    const int bx = blockIdx.x;
    gemm_mfma_body<0>(Ah, Al, Bh, Bl, A, W, bias, resid, C, nullptr, nullptr,
                      (long)(bx >> 2) * 128, (bx & 3) * 128);
}

// ---------------------------------------------------------------------------
// MFMA flash attention v2: occupancy-restructured (UNCHANGED from round 12).
// Block = 32 q-rows, 4 waves split keys 4-way (wave w: kt=128t+32w,
// IDENTICAL key partition/order as v1 -> bit-identical results). Grid 1024.
// LDS 37.9KB (Obuf[4][64][36]) -> 4 blocks/CU = 16 waves/CU (was 8).
// ---------------------------------------------------------------------------
__global__ __launch_bounds__(256, 4) void attn_kernel(const float* __restrict__ qp,
                                                      const short* __restrict__ kbh,
                                                      const short* __restrict__ kbl,
                                                      const short* __restrict__ vth,
                                                      const short* __restrict__ vtl,
                                                      const int* __restrict__ mask,
                                                      float* __restrict__ o)
{
    __shared__ float Obuf[4][64][36];
    __shared__ float mlbuf[4][2][32];

    const int tid = threadIdx.x;
    const int l   = tid & 63;
    const int w   = tid >> 6;
    const int lq  = l & 31;
    const int hi  = l >> 5;

    const int wg  = (blockIdx.x & 7) * 128 + (blockIdx.x >> 3);  // XCD swizzle (1024=8x128)
    const int q0  = (wg & 31) * 32;
    const int bh  = wg >> 5;
    const int b   = bh >> 3, h = bh & 7;

    // hoist Q fragments (scale 0.125 folded), hi/lo split
    s16x8 Qh[4], Ql[4];
#pragma unroll
    for (int ks = 0; ks < 4; ++ks) {
        const float* src = qp + ((long)(b * LQ + q0 + lq)) * DM + h * DK + ks * 16 + hi * 8;
        float4 f0 = *(const float4*)src;
        float4 f1 = *(const float4*)(src + 4);
        float ff[8] = {f0.x, f0.y, f0.z, f0.w, f1.x, f1.y, f1.z, f1.w};
        U32x4 Hh, Ll;
#pragma unroll
        for (int i = 0; i < 4; ++i) {
            short h0, l0, h1, l1;
            cvt_split(ff[2 * i] * 0.125f, h0, l0);
            cvt_split(ff[2 * i + 1] * 0.125f, h1, l1);
            Hh.u[i] = (unsigned short)h0 | ((unsigned)(unsigned short)h1 << 16);
            Ll.u[i] = (unsigned short)l0 | ((unsigned)(unsigned short)l1 << 16);
        }
        Qh[ks] = Hh.v; Ql[ks] = Ll.v;
    }

    const short* kbase_h = kbh + (long)bh * 2048 * 64;
    const short* kbase_l = kbl + (long)bh * 2048 * 64;
    const short* vbase_h = vth + (long)bh * 64 * 2048;
    const short* vbase_l = vtl + (long)bh * 64 * 2048;
    const int*   mrow    = mask + b * LK;

    float m_run = -1e30f;
    float l_run = 0.f;
    f32x16 Oa[2];   // [md] O^T[d][q]
#pragma unroll
    for (int md = 0; md < 2; ++md)
#pragma unroll
        for (int e = 0; e < 16; ++e) Oa[md][e] = 0.f;

    for (int t = 0; t < 16; ++t) {
        const int kt = t * 128 + w * 32;
        const unsigned long long mb = __ballot(mrow[kt + lq] != 0);
        const unsigned mbits = (unsigned)mb;

        // S^T = K . Q^T (3-term split)
        f32x16 S;
#pragma unroll
        for (int e = 0; e < 16; ++e) S[e] = 0.f;
#pragma unroll
        for (int ks = 0; ks < 4; ++ks) {
            s16x8 Kh = *(const s16x8*)(kbase_h + (long)(kt + lq) * 64 + ks * 16 + hi * 8);
            s16x8 Kl = *(const s16x8*)(kbase_l + (long)(kt + lq) * 64 + ks * 16 + hi * 8);
            S = __builtin_amdgcn_mfma_f32_32x32x16_bf16(Kh, Qh[ks], S, 0, 0, 0);
            S = __builtin_amdgcn_mfma_f32_32x32x16_bf16(Kh, Ql[ks], S, 0, 0, 0);
            S = __builtin_amdgcn_mfma_f32_32x32x16_bf16(Kl, Qh[ks], S, 0, 0, 0);
        }

        // online softmax (keys of this tile live in lanes l and l^32)
        float sv[16];
#pragma unroll
        for (int r = 0; r < 16; ++r) {
            int key = (r & 3) + 8 * (r >> 2) + 4 * hi;
            sv[r] = ((mbits >> key) & 1u) ? S[r] : -1e30f;
        }
        float mx = sv[0];
#pragma unroll
        for (int r = 1; r < 16; ++r) mx = fmaxf(mx, sv[r]);
        mx = fmaxf(mx, __shfl_xor(mx, 32));
        float m_new = fmaxf(m_run, mx);
        float al = __expf(m_run - m_new);
        m_run = m_new;
        float pv[16], ps = 0.f;
#pragma unroll
        for (int r = 0; r < 16; ++r) {
            int key = (r & 3) + 8 * (r >> 2) + 4 * hi;
            float p = ((mbits >> key) & 1u) ? __expf(sv[r] - m_new) : 0.f;
            pv[r] = p; ps += p;
        }
        ps += __shfl_xor(ps, 32);
        l_run = l_run * al + ps;
#pragma unroll
        for (int md = 0; md < 2; ++md)
#pragma unroll
            for (int e = 0; e < 16; ++e) Oa[md][e] *= al;
        unsigned pk_[8], xk[8];
#pragma unroll
        for (int i = 0; i < 8; ++i) pk_[i] = pack_bf16(pv[2 * i], pv[2 * i + 1]);
#pragma unroll
        for (int i = 0; i < 8; ++i) xk[i] = (unsigned)__shfl_xor((int)pk_[i], 32);

        // PV: O^T += V^T . P^T  (V split hi/lo)
#pragma unroll
        for (int ks = 0; ks < 2; ++ks) {
            U32x4 u;
            if (hi == 0) {
                u.u[0] = pk_[4 * ks];     u.u[1] = pk_[4 * ks + 1];
                u.u[2] = xk[4 * ks];      u.u[3] = xk[4 * ks + 1];
            } else {
                u.u[0] = xk[4 * ks + 2];  u.u[1] = xk[4 * ks + 3];
                u.u[2] = pk_[4 * ks + 2]; u.u[3] = pk_[4 * ks + 3];
            }
            s16x8 Pf = u.v;
#pragma unroll
            for (int md = 0; md < 2; ++md) {
                s16x8 Vh = *(const s16x8*)(vbase_h + (long)(32 * md + lq) * 2048 + kt + ks * 16 + hi * 8);
                s16x8 Vl = *(const s16x8*)(vbase_l + (long)(32 * md + lq) * 2048 + kt + ks * 16 + hi * 8);
                Oa[md] = __builtin_amdgcn_mfma_f32_32x32x16_bf16(Vh, Pf, Oa[md], 0, 0, 0);
                Oa[md] = __builtin_amdgcn_mfma_f32_32x32x16_bf16(Vl, Pf, Oa[md], 0, 0, 0);
            }
        }
    }

    // stash per-wave partials
#pragma unroll
    for (int md = 0; md < 2; ++md)
#pragma unroll
        for (int r = 0; r < 16; ++r) {
            int d = 32 * md + (r & 3) + 8 * (r >> 2) + 4 * hi;
            Obuf[w][d][lq] = Oa[md][r];
        }
    if (l < 32) {
        mlbuf[w][0][lq] = m_run;
        mlbuf[w][1][lq] = l_run;
    }
    __syncthreads();

    // combine across waves: thread -> (q = tid&31, d-chunk = tid>>5 of 8)
    {
        const int q  = tid & 31;
        const int dc = tid >> 5;
        float mw[4], lw[4];
#pragma unroll
        for (int w2 = 0; w2 < 4; ++w2) {
            mw[w2] = mlbuf[w2][0][q];
            lw[w2] = mlbuf[w2][1][q];
        }
        float ms = fmaxf(fmaxf(mw[0], mw[1]), fmaxf(mw[2], mw[3]));
        float fw[4], Ls = 0.f;
#pragma unroll
        for (int w2 = 0; w2 < 4; ++w2) { fw[w2] = __expf(mw[w2] - ms); Ls += lw[w2] * fw[w2]; }
        float inv = 1.f / Ls;
        float ov[8];
#pragma unroll
        for (int dd = 0; dd < 8; ++dd) {
            int d = dc * 8 + dd;
            float a = Obuf[0][d][q] * fw[0] + Obuf[1][d][q] * fw[1] +
                      Obuf[2][d][q] * fw[2] + Obuf[3][d][q] * fw[3];
            ov[dd] = a * inv;
        }
        float* dst = o + ((long)(b * LQ + q0 + q)) * DM + h * DK + dc * 8;
        *(float4*)(dst + 0) = *(float4*)&ov[0];
        *(float4*)(dst + 4) = *(float4*)&ov[4];
    }
}

// ---------------------------------------------------------------------------
// LayerNorm over last dim (512). One wave per row; 8 floats per lane.
// ---------------------------------------------------------------------------
__global__ __launch_bounds__(256) void ln_kernel(const float* __restrict__ x,
                                                 const float* __restrict__ gamma,
                                                 const float* __restrict__ beta,
                                                 float* __restrict__ out)
{
    const int wave = threadIdx.x >> 6;
    const int lane = threadIdx.x & 63;
    const long row = (long)blockIdx.x * 4 + wave;
    const float* xr = x + row * DM + lane * 8;
    float4 a = *(const float4*)xr;
    float4 b = *(const float4*)(xr + 4);
    float sum = a.x + a.y + a.z + a.w + b.x + b.y + b.z + b.w;
    float sq  = a.x * a.x + a.y * a.y + a.z * a.z + a.w * a.w +
                b.x * b.x + b.y * b.y + b.z * b.z + b.w * b.w;
#pragma unroll
    for (int m = 1; m < 64; m <<= 1) {
        sum += __shfl_xor(sum, m);
        sq  += __shfl_xor(sq, m);
    }
    const float mu  = sum * (1.f / 512.f);
    const float var = sq * (1.f / 512.f) - mu * mu;
    const float rs  = 1.0f / sqrtf(var + LN_EPS);

    float4 g0 = *(const float4*)(gamma + lane * 8);
    float4 g1 = *(const float4*)(gamma + lane * 8 + 4);
    float4 t0 = *(const float4*)(beta + lane * 8);
    float4 t1 = *(const float4*)(beta + lane * 8 + 4);
    float4 o0 = make_float4((a.x - mu) * rs * g0.x + t0.x,
                            (a.y - mu) * rs * g0.y + t0.y,
                            (a.z - mu) * rs * g0.z + t0.z,
                            (a.w - mu) * rs * g0.w + t0.w);
    float4 o1 = make_float4((b.x - mu) * rs * g1.x + t1.x,
                            (b.y - mu) * rs * g1.y + t1.y,
                            (b.z - mu) * rs * g1.z + t1.z,
                            (b.w - mu) * rs * g1.w + t1.w);
    *(float4*)(out + row * DM + lane * 8) = o0;
    *(float4*)(out + row * DM + lane * 8 + 4) = o1;
}

// ---------------------------------------------------------------------------
extern "C" void kernel_launch(void* const* d_in, const int* in_sizes, int n_in,
                              void* d_out, int out_size, void* d_ws, size_t ws_size,
                              hipStream_t stream)
{
    const float* Q    = (const float*)d_in[0];
    const float* K    = (const float*)d_in[1];
    const float* V    = (const float*)d_in[2];
    // d_in[3] = node_num (unused; Lk fixed at 2048)
    const int*   mask = (const int*)d_in[4];
    const float* Wq   = (const float*)d_in[5];
    const float* bq   = (const float*)d_in[6];
    const float* Wk   = (const float*)d_in[7];
    const float* bk   = (const float*)d_in[8];
    const float* Wv   = (const float*)d_in[9];
    const float* bv   = (const float*)d_in[10];
    const float* Wo   = (const float*)d_in[11];
    const float* bo   = (const float*)d_in[12];
    const float* gamma= (const float*)d_in[13];
    const float* beta = (const float*)d_in[14];
    float* out = (float*)d_out;

    char* base = (char*)d_ws;
    float* qp  = (float*)(base);                             // 8 MB (4096x512 f32)
    short* kbh = (short*)(base + (size_t)8  * 1024 * 1024);  // 8 MB
    short* kbl = (short*)(base + (size_t)16 * 1024 * 1024);  // 8 MB
    short* vth = (short*)(base + (size_t)24 * 1024 * 1024);  // 8 MB
    short* vtl = (short*)(base + (size_t)32 * 1024 * 1024);  // 8 MB
    float* ao  = (float*)(base + (size_t)40 * 1024 * 1024);  // 8 MB
    float* tmp = (float*)(base + (size_t)48 * 1024 * 1024);  // 8 MB

    qkv_kernel<<<640, 256, 0, stream>>>(Q, K, V, Wq, bq, Wk, bk, Wv, bv,
                                        qp, kbh, kbl, vth, vtl);
    attn_kernel<<<1024, 256, 0, stream>>>(qp, kbh, kbl, vth, vtl, mask, ao);
    ogemm_kernel<<<128, 256, 0, stream>>>(ao, Wo, bo, Q, tmp);
    ln_kernel<<<1024, 256, 0, stream>>>(tmp, gamma, beta, out);
}